// Round 18
// baseline (372.867 us; speedup 1.0000x reference)
//
#include <hip/hip_runtime.h>
#include <hip/hip_bf16.h>
#include <math.h>

// ExpertChoiceMoELayer: B=8,S=2048,D=1024,F=2048,E=8 -> T=16384, cap=2048
#define T_TOK 16384
#define DIM   1024
#define FF    2048
#define NE    8
#define CAPK  2048
#define WL1SZ 4096   // 8 experts x 512 (mt x nt16) 128-row tiles
#define WL2SZ 2048   // 8 experts x 256 (mt x nt8)
#define NB_W2T 4096  // W2 transpose blocks appended to ffn1 launch

typedef unsigned short u16;
typedef unsigned long long u64;
typedef __attribute__((ext_vector_type(8))) short bf16x8;
typedef __attribute__((ext_vector_type(4))) float f32x4;

__device__ __forceinline__ u16 f2bf(float f) {
  __hip_bfloat16 h = __float2bfloat16(f);
  union { __hip_bfloat16 h; u16 u; } c; c.h = h; return c.u;
}

// fast GELU: 0.5x(1+erf(x/sqrt2)), erf via Abramowitz-Stegun 7.1.26 (|err|<=1.5e-7)
__device__ __forceinline__ float gelu_f(float v) {
  float z = fabsf(v) * 0.70710678118654752f;
  float t = __builtin_amdgcn_rcpf(1.0f + 0.3275911f * z);
  float poly = t * (0.254829592f +
               t * (-0.284496736f +
               t * (1.421413741f +
               t * (-1.453152027f +
               t * 1.061405429f))));
  float ez = __expf(-z * z);
  float erfz = 1.0f - poly * ez;
  erfz = copysignf(erfz, v);
  return 0.5f * v * (1.0f + erfz);
}

__device__ __forceinline__ void async_copy16(const void* g, void* l) {
  __builtin_amdgcn_global_load_lds(
      (const __attribute__((address_space(1))) unsigned int*)g,
      (__attribute__((address_space(3))) unsigned int*)l, 16, 0, 0);
}

// opaque LDS read (rule #18 discipline): ordering enforced by our asm waits
__device__ __forceinline__ bf16x8 ds_read16(const char* p) {
  bf16x8 r;
  asm volatile("ds_read_b128 %0, %1"
               : "=&v"(r)
               : "v"((const __attribute__((address_space(3))) char*)p));
  return r;
}

#define LGKM0()                                                                   \
  do {                                                                            \
    asm volatile("s_waitcnt lgkmcnt(0)" ::: "memory");                            \
    __builtin_amdgcn_sched_barrier(0);                                            \
  } while (0)
#define VMW0() asm volatile("s_waitcnt vmcnt(0)" ::: "memory")
#define BAR() asm volatile("s_barrier" ::: "memory")

// generic 64x64 fp32->bf16 transpose tile body (shared by prep W1T and ffn1 W2T)
__device__ __forceinline__ void transpose_tile(const float* __restrict__ src,
                                               u16* __restrict__ dst, int R, int C,
                                               int bxy, int tid, float (*tile)[65]) {
  int nbx = C >> 6;
  int bx = bxy % nbx, by = bxy / nbx;
  int r0 = by * 64, c0 = bx * 64;
  int lr = tid >> 4, lc4 = (tid & 15) * 4;
#pragma unroll
  for (int p = 0; p < 4; ++p) {
    float4 v = *(const float4*)(src + (size_t)(r0 + p * 16 + lr) * C + c0 + lc4);
    tile[p * 16 + lr][lc4 + 0] = v.x;
    tile[p * 16 + lr][lc4 + 1] = v.y;
    tile[p * 16 + lr][lc4 + 2] = v.z;
    tile[p * 16 + lr][lc4 + 3] = v.w;
  }
  __syncthreads();
  int oc = tid >> 3, orr = (tid & 7) * 8;
#pragma unroll
  for (int p = 0; p < 2; ++p) {
    int c = p * 32 + oc;
    u16 h[8];
#pragma unroll
    for (int j = 0; j < 8; ++j) h[j] = f2bf(tile[orr + j][c]);
    *(uint4*)(dst + (size_t)(c0 + c) * R + r0 + orr) = *(uint4*)h;
  }
}

// ===== K1: merged router (bid<4096) + W1 transpose (bid>=4096) =====
// routers do NOT fence — kernel boundary is the sync point (R12/R16 lesson).
__global__ __launch_bounds__(256) void prep_k(const float* __restrict__ x,
                                              const float* __restrict__ Wg,
                                              const float* __restrict__ W1,
                                              float* __restrict__ probs,
                                              float* __restrict__ probsT,
                                              u16* __restrict__ xb,
                                              u16* __restrict__ w1t,
                                              u64* __restrict__ key,
                                              int* cnt, int* cnt2, int* gates) {
  __shared__ float tile[64][65];
  int bid = blockIdx.x, tid = threadIdx.x;
  if (bid < 4096) {
    if (tid < 4) key[bid * 4 + tid] = 0ull;
    if (bid == 0 && tid < NE) { cnt[tid] = 0; cnt2[tid] = 0; }
    if (bid == 0 && tid >= 8 && tid < 10) gates[tid - 8] = 0;
    int wid = tid >> 6, lane = tid & 63;
    int t = bid * 4 + wid;
    const float* xr = x + (size_t)t * DIM;
    u16* xbr = xb + (size_t)t * DIM;
    double acc[NE] = {0, 0, 0, 0, 0, 0, 0, 0};
#pragma unroll
    for (int it = 0; it < DIM / 64; ++it) {
      int d = it * 64 + lane;
      float xv = xr[d];
      xbr[d] = f2bf(xv);
      const float4* wrow = (const float4*)(Wg + (size_t)d * NE);
      float4 w0 = wrow[0], w1 = wrow[1];
      acc[0] += (double)xv * (double)w0.x;
      acc[1] += (double)xv * (double)w0.y;
      acc[2] += (double)xv * (double)w0.z;
      acc[3] += (double)xv * (double)w0.w;
      acc[4] += (double)xv * (double)w1.x;
      acc[5] += (double)xv * (double)w1.y;
      acc[6] += (double)xv * (double)w1.z;
      acc[7] += (double)xv * (double)w1.w;
    }
#pragma unroll
    for (int e = 0; e < NE; ++e)
      for (int o = 32; o > 0; o >>= 1) acc[e] += __shfl_down(acc[e], o, 64);
    if (lane == 0) {
      float l[NE], mx = -3.0e38f;
#pragma unroll
      for (int e = 0; e < NE; ++e) { l[e] = (float)acc[e]; mx = fmaxf(mx, l[e]); }
      float s = 0.f;
#pragma unroll
      for (int e = 0; e < NE; ++e) { l[e] = expf(l[e] - mx); s += l[e]; }
      float inv = 1.0f / s;
#pragma unroll
      for (int e = 0; e < NE; ++e) {
        float p = l[e] * inv;
        probs[(size_t)t * NE + e] = p;
        probsT[(size_t)e * T_TOK + t] = p;
      }
    }
  } else {
    int tz = bid - 4096;            // 0..4095
    int z = tz >> 9, bxy = tz & 511;
    transpose_tile(W1 + (size_t)z * DIM * FF, w1t + (size_t)z * DIM * FF,
                   DIM, FF, bxy, tid, tile);
  }
}

// ===== K2: merged topk(8 blocks) + assign+slot (64 blocks, internal gate) =====
__global__ __launch_bounds__(256) void moe_route_k(const float* __restrict__ probsT,
                                                   const float* __restrict__ probs,
                                                   u64* __restrict__ key,
                                                   int* __restrict__ tok2exp,
                                                   float* __restrict__ wgt,
                                                   int* cnt, int* cnt2,
                                                   int* __restrict__ list,
                                                   int* basep, int* wl1, int* wl2,
                                                   int* gates) {
  __shared__ float pcol[T_TOK];
  __shared__ unsigned whist[8][2048];
  __shared__ unsigned hist[2048];
  __shared__ unsigned bcast[2];
  __shared__ unsigned wsum[4];
  __shared__ int wps[4];
  int bid = blockIdx.x, tid = threadIdx.x, wid = tid >> 6, lane = tid & 63;
  if (bid < 8) {
    int e = bid;
    const float4* src4 = (const float4*)(probsT + (size_t)e * T_TOK);
    for (int i = tid; i < T_TOK / 4; i += 256) ((float4*)pcol)[i] = src4[i];
    for (int i = tid; i < 8 * 2048; i += 256) ((unsigned*)whist)[i] = 0;
    unsigned prefix = 0, remaining = CAPK;
#pragma unroll 1
    for (int lvl = 0; lvl < 3; ++lvl) {
      int nb = (lvl == 2) ? 1024 : 2048;
      if (lvl == 0) {
        __syncthreads();
        for (int i = tid; i < T_TOK; i += 256)
          atomicAdd(&whist[wid][__float_as_uint(pcol[i]) >> 21], 1u);
        __syncthreads();
        for (int j = tid; j < 2048; j += 256) {
          unsigned s2 = 0;
#pragma unroll
          for (int w = 0; w < 8; ++w) s2 += whist[w][j];
          hist[j] = s2;
        }
        __syncthreads();
      } else {
        for (int i = tid; i < 2048; i += 256) hist[i] = 0;
        __syncthreads();
        for (int i = tid; i < T_TOK; i += 256) {
          unsigned k = __float_as_uint(pcol[i]);
          bool m = (lvl == 1) ? ((k >> 21) == prefix) : ((k >> 10) == prefix);
          if (m) atomicAdd(&hist[(lvl == 1) ? ((k >> 10) & 2047u) : (k & 1023u)], 1u);
        }
        __syncthreads();
      }
      int nper = nb / 256;
      unsigned cv = 0;
      for (int j = 0; j < nper; ++j) cv += hist[tid * nper + j];
      unsigned s = cv;
#pragma unroll
      for (int o = 1; o < 64; o <<= 1) {
        unsigned tv = __shfl_down(s, o, 64);
        if (lane + o < 64) s += tv;
      }
      if (lane == 0) wsum[wid] = s;
      __syncthreads();
      unsigned above = 0;
      for (int w = wid + 1; w < 4; ++w) above += wsum[w];
      unsigned Sincl = s + above, Sexcl = Sincl - cv;
      if (Sincl >= remaining && Sexcl < remaining) {
        unsigned rem2 = remaining - Sexcl, cum2 = 0;
        for (int j = nper - 1; j >= 0; --j) {
          unsigned h = hist[tid * nper + j];
          if (cum2 + h >= rem2) { bcast[0] = (unsigned)(tid * nper + j); bcast[1] = rem2 - cum2; break; }
          cum2 += h;
        }
      }
      __syncthreads();
      unsigned b = bcast[0];
      remaining = bcast[1];
      prefix = (lvl == 0) ? b : (lvl == 1) ? ((prefix << 11) | b) : ((prefix << 10) | b);
      __syncthreads();
    }
    unsigned vk = prefix;
    int need = (int)remaining;
    const int CH = T_TOK / 256;
    int i0 = tid * CH;
    int myt = 0;
    for (int i = i0; i < i0 + CH; ++i)
      myt += (__float_as_uint(pcol[i]) == vk);
    int p = myt;
#pragma unroll
    for (int o = 1; o < 64; o <<= 1) {
      int tv = __shfl_up(p, o, 64);
      if (lane >= o) p += tv;
    }
    if (lane == 63) wps[wid] = p;
    __syncthreads();
    int wo = 0;
    for (int w = 0; w < wid; ++w) wo += wps[w];
    int run = wo + p - myt;
    u64 ebits = (u64)(7 - e);
    for (int i = i0; i < i0 + CH; ++i) {
      unsigned k = __float_as_uint(pcol[i]);
      bool sv = false;
      if (k > vk) sv = true;
      else if (k == vk) { if (run < need) sv = true; run++; }
      if (sv) atomicMax(&key[i], ((u64)k << 3) | ebits);
    }
    __threadfence();
    __syncthreads();
    if (tid == 0) atomicAdd(&gates[0], 1);
  } else {
    if (tid == 0) {
      while (atomicAdd(&gates[0], 0) < 8) __builtin_amdgcn_s_sleep(8);
    }
    __syncthreads();
    __threadfence();
    int gid = (bid - 8) * 256 + tid;
    u64 k = key[gid];
    int best;
    float bp;
    if (k) {
      best = 7 - (int)(k & 7);
      bp = __uint_as_float((unsigned)(k >> 3));
    } else {
      best = 0; bp = -3.0e38f;
#pragma unroll
      for (int e = 0; e < NE; ++e) {
        float p = probs[(size_t)gid * NE + e];
        if (p > bp) { bp = p; best = e; }
      }
    }
    tok2exp[gid] = best;
    wgt[gid] = bp;
#pragma unroll
    for (int e = 0; e < NE; ++e) {
      u64 m = __ballot(best == e);
      if (best == e && lane == __ffsll(m) - 1) atomicAdd(&cnt[e], (int)__popcll(m));
    }
    __threadfence();
    __syncthreads();
    if (tid == 0) atomicAdd(&gates[1], 1);
    if (tid == 0) {
      while (atomicAdd(&gates[1], 0) < 64) __builtin_amdgcn_s_sleep(8);
    }
    __syncthreads();
    __threadfence();
    int c[NE];
#pragma unroll
    for (int e = 0; e < NE; ++e) c[e] = cnt[e];
    if (gid < NE) {
      int r = 0;
      for (int e = 0; e < gid; ++e) r += c[e];
      basep[gid] = r;
    }
    if (gid < WL1SZ) {
      int e = gid & 7, j = gid >> 3;      // j 0..511
      int mte = (c[e] + 127) >> 7;
      wl1[gid] = (j < mte * 16) ? (e | ((j >> 4) << 4) | ((j & 15) << 12)) : -1;
    }
    if (gid >= WL1SZ && gid < WL1SZ + WL2SZ) {
      int g2 = gid - WL1SZ;
      int e = g2 & 7, j = g2 >> 3;        // j 0..255
      int mte = (c[e] + 127) >> 7;
      wl2[g2] = (j < mte * 8) ? (e | ((j >> 3) << 4) | ((j & 7) << 12)) : -1;
    }
    int te = tok2exp[gid];
    int bp_e = 0;
#pragma unroll
    for (int e = 0; e < NE; ++e) if (e < te) bp_e += c[e];
    int sl = 0;
#pragma unroll
    for (int e = 0; e < NE; ++e) {
      u64 m = __ballot(te == e);
      if (te == e) {
        int leader = __ffsll(m) - 1;
        int rank = __popcll(m & ((1ull << lane) - 1));
        int b = 0;
        if (lane == leader) b = atomicAdd(&cnt2[e], (int)__popcll(m));
        b = __shfl(b, leader, 64);
        sl = bp_e + b + rank;
      }
    }
    list[sl] = gid;
  }
}

// ===== FFN: 128x128 tile, BK=32, DOUBLE-buffered 2x16KB (32KB total) =====
// -> still 4 blocks/CU, but prefetch-1-ahead: the vmcnt(0) drain now waits on
// loads issued one full MFMA phase (~400cyc) earlier instead of immediately
// before. ONE barrier per tile. Swizzle algebra = R11 (verified), flow = R17.
// EPI=0: H[slot] = GELU(xb[tok] @ W1t^T); blocks >= WL1SZ do W2 transpose
// EPI=1: out[tok] = wgt * (H[slot] @ W2t^T)

#define MF(M, N_, AV, BV) acc[M][N_] = __builtin_amdgcn_mfma_f32_16x16x32_bf16(BV, AV, acc[M][N_], 0, 0, 0)

#define STG(b, kt)                                                                \
  do {                                                                            \
    char* base = sm + (b) * 16384;                                                \
    size_t ko = (size_t)(kt) * 64;                                                \
    async_copy16(aP0 + ko, base + tid * 16);                                      \
    async_copy16(aP1 + ko, base + 4096 + tid * 16);                               \
    async_copy16(bP0 + ko, base + 8192 + tid * 16);                               \
    async_copy16(bP1 + ko, base + 12288 + tid * 16);                              \
  } while (0)

#define DSRD(b)                                                                   \
  do {                                                                            \
    const char* pa = sm + (b) * 16384 + wr * 4096 + laneOff;                      \
    const char* pb = sm + (b) * 16384 + 8192 + wc * 4096 + laneOff;               \
    a0 = ds_read16(pa);        a1 = ds_read16(pa + 1024);                         \
    a2 = ds_read16(pa + 2048); a3 = ds_read16(pa + 3072);                         \
    b0 = ds_read16(pb);        b1 = ds_read16(pb + 1024);                         \
    b2 = ds_read16(pb + 2048); b3 = ds_read16(pb + 3072);                         \
  } while (0)

#define MFMA16()                                                                  \
  do {                                                                            \
    __builtin_amdgcn_s_setprio(1);                                                \
    MF(0, 0, a0, b0); MF(0, 1, a0, b1); MF(0, 2, a0, b2); MF(0, 3, a0, b3);       \
    MF(1, 0, a1, b0); MF(1, 1, a1, b1); MF(1, 2, a1, b2); MF(1, 3, a1, b3);       \
    MF(2, 0, a2, b0); MF(2, 1, a2, b1); MF(2, 2, a2, b2); MF(2, 3, a2, b3);       \
    MF(3, 0, a3, b0); MF(3, 1, a3, b1); MF(3, 2, a3, b2); MF(3, 3, a3, b3);       \
    __builtin_amdgcn_s_setprio(0);                                                \
  } while (0)

template <int EPI>
__global__ __launch_bounds__(256, 4) void ffn_k(const u16* __restrict__ A,
                                                const u16* __restrict__ Bm,
                                                void* __restrict__ Out,
                                                const int* __restrict__ list,
                                                const float* __restrict__ wgt,
                                                const int* __restrict__ basep,
                                                const int* __restrict__ cnt,
                                                const int* __restrict__ wl,
                                                const float* __restrict__ W2f,
                                                u16* __restrict__ w2t) {
  constexpr int K = EPI ? FF : DIM;
  constexpr int N = EPI ? DIM : FF;
  constexpr int KT = K / 32;

  __shared__ u16 smem[16384];   // 32 KiB: 2 x (A 8KB + B 8KB) / transpose alias
  __shared__ int toks[128];
  __shared__ float wsc[128];
  char* const sm = (char*)smem;
  const int tid = threadIdx.x;

  if (EPI == 0 && blockIdx.x >= WL1SZ) {
    // ---- W2 transpose role: fp32 [E][F][D] -> bf16 [E][D][F] ----
    int tz = blockIdx.x - WL1SZ;    // 0..4095
    int z = tz >> 9, bxy = tz & 511;
    transpose_tile(W2f + (size_t)z * FF * DIM, w2t + (size_t)z * FF * DIM,
                   FF, DIM, bxy, tid, (float (*)[65])sm);
    return;
  }

  const int wle = wl[blockIdx.x];
  if (wle < 0) return;
  const int e = wle & 15, mt = (wle >> 4) & 255, nt = wle >> 12;
  const int ce = cnt[e];
  const int be = basep[e];

  if (tid < 128) {
    int r = mt * 128 + tid;
    int tk = (r < ce) ? list[be + r] : list[be];
    toks[tid] = tk;
    if (EPI == 1) wsc[tid] = wgt[tk];
  }
  __syncthreads();

  const int wid = tid >> 6, lane = tid & 63;
  const int wr = wid >> 1, wc = wid & 1;
  // 64B-row swizzle (R11-verified): frag row = lane&15, k-slot s = lane>>4;
  // phys slot = s ^ ((row>>1)&3)  (2-way aliasing = free per m136)
  const int laneOff = (lane & 15) * 64 +
                      (((lane >> 4) ^ (((lane & 15) >> 1) & 3)) << 4);

  // staging: thread covers rows r0 and r0+64; inverse-swizzled source slot
  const int r0 = tid >> 2;                               // 0..63
  const int cbl = (((tid & 3) ^ ((tid >> 3) & 3)) << 4); // source byte-in-row
  const char *aP0, *aP1;
  if (EPI == 0) {
    aP0 = (const char*)(A + (size_t)toks[r0] * K) + cbl;
    aP1 = (const char*)(A + (size_t)toks[r0 + 64] * K) + cbl;
  } else {
    aP0 = (const char*)(A + ((size_t)be + mt * 128 + r0) * K) + cbl;
    aP1 = (const char*)(A + ((size_t)be + mt * 128 + r0 + 64) * K) + cbl;
  }
  const char* bP0 = (const char*)(Bm + ((size_t)e * N + nt * 128 + r0) * K) + cbl;
  const char* bP1 = (const char*)(Bm + ((size_t)e * N + nt * 128 + r0 + 64) * K) + cbl;

  f32x4 acc[4][4];
#pragma unroll
  for (int m = 0; m < 4; ++m)
#pragma unroll
    for (int n = 0; n < 4; ++n) acc[m][n] = (f32x4){0.f, 0.f, 0.f, 0.f};

  bf16x8 a0, a1, a2, a3, b0, b1, b2, b3;

  // prologue: stage tile 0 into buf 0
  STG(0, 0);
  VMW0();
  BAR();

#pragma unroll 1
  for (int kt = 0; kt < KT; ++kt) {
    const int cb = kt & 1, nb = cb ^ 1;
    if (kt + 1 < KT) STG(nb, kt + 1);  // prefetch next tile into other buffer
    DSRD(cb);                          // 8 frag reads from current buffer
    LGKM0();
    MFMA16();                          // ~400 cyc — prefetch lands underneath
    VMW0();                            // drains the 4 loads issued above
    BAR();                             // reads of cb done + nb visible to all
  }

  // epilogue: operand-swap => acc reg index runs along output cols -> vector stores
  const int lc = lane & 15, lq = (lane >> 4) * 4;
#pragma unroll
  for (int m = 0; m < 4; ++m) {
    int trow = wr * 64 + m * 16 + lc;
    int grow = mt * 128 + trow;
    if (grow < ce) {
      if (EPI == 0) {
        size_t rowoff = (size_t)(be + grow) * FF + nt * 128 + wc * 64 + lq;
#pragma unroll
        for (int n = 0; n < 4; ++n) {
          ushort4 h4;
          h4.x = f2bf(gelu_f(acc[m][n][0]));
          h4.y = f2bf(gelu_f(acc[m][n][1]));
          h4.z = f2bf(gelu_f(acc[m][n][2]));
          h4.w = f2bf(gelu_f(acc[m][n][3]));
          *(ushort4*)((u16*)Out + rowoff + n * 16) = h4;
        }
      } else {
        float w = wsc[trow];
        size_t rowoff = (size_t)toks[trow] * DIM + nt * 128 + wc * 64 + lq;
#pragma unroll
        for (int n = 0; n < 4; ++n) {
          float4 o = make_float4(w * acc[m][n][0], w * acc[m][n][1],
                                 w * acc[m][n][2], w * acc[m][n][3]);
          *(float4*)((float*)Out + rowoff + n * 16) = o;
        }
      }
    }
  }
}

extern "C" void kernel_launch(void* const* d_in, const int* in_sizes, int n_in,
                              void* d_out, int out_size, void* d_ws, size_t ws_size,
                              hipStream_t stream) {
  (void)in_sizes; (void)n_in; (void)out_size; (void)ws_size;
  const float* x  = (const float*)d_in[0];
  const float* Wg = (const float*)d_in[1];
  const float* W1 = (const float*)d_in[2];
  const float* W2 = (const float*)d_in[3];
  float* out = (float*)d_out;

  char* ws = (char*)d_ws;
  size_t off = 0;
  auto alloc = [&](size_t bytes) -> void* {
    void* p = ws + off;
    off += (bytes + 255) & ~(size_t)255;
    return p;
  };
  u16* xb   = (u16*)alloc((size_t)T_TOK * DIM * 2);         // 32 MB
  u16* w1t  = (u16*)alloc((size_t)NE * FF * DIM * 2);       // 32 MB  [E][F][D]
  u16* w2t  = (u16*)alloc((size_t)NE * DIM * FF * 2);       // 32 MB  [E][D][F]
  u16* H    = (u16*)alloc((size_t)(T_TOK + 256) * FF * 2);  // 65 MB, padded
  float* probs  = (float*)alloc((size_t)T_TOK * NE * 4);
  float* probsT = (float*)alloc((size_t)NE * T_TOK * 4);
  u64* key      = (u64*)alloc((size_t)T_TOK * 8);
  float* wgt    = (float*)alloc((size_t)T_TOK * 4);
  int* tok2exp  = (int*)alloc((size_t)T_TOK * 4);
  int* list     = (int*)alloc((size_t)T_TOK * 4);
  int* cnt      = (int*)alloc(64);
  int* cnt2     = (int*)alloc(64);
  int* basep    = (int*)alloc(64);
  int* gates    = (int*)alloc(64);
  int* wl1      = (int*)alloc(WL1SZ * 4);
  int* wl2      = (int*)alloc(WL2SZ * 4);

  prep_k<<<4096 + 4096, 256, 0, stream>>>(x, Wg, W1, probs, probsT, xb, w1t,
                                          key, cnt, cnt2, gates);
  moe_route_k<<<72, 256, 0, stream>>>(probsT, probs, key, tok2exp, wgt, cnt, cnt2,
                                      list, basep, wl1, wl2, gates);
  ffn_k<0><<<WL1SZ + NB_W2T, 256, 0, stream>>>(xb, w1t, H, list, wgt, basep, cnt, wl1,
                                               W2, w2t);
  ffn_k<1><<<WL2SZ, 256, 0, stream>>>(H, w2t, out, list, wgt, basep, cnt, wl2,
                                      W2, w2t);
}

// Round 19
// 349.942 us; speedup vs baseline: 1.0655x; 1.0655x over previous
//
#include <hip/hip_runtime.h>
#include <hip/hip_bf16.h>
#include <math.h>

// ExpertChoiceMoELayer: B=8,S=2048,D=1024,F=2048,E=8 -> T=16384, cap=2048
#define T_TOK 16384
#define DIM   1024
#define FF    2048
#define NE    8
#define CAPK  2048
#define WL1SZ 4096   // 8 experts x 512 (mt x nt16) 128-row tiles
#define WL2SZ 2048   // 8 experts x 256 (mt x nt8)
#define NB_W2T 4096  // W2 transpose blocks appended to ffn1 launch

typedef unsigned short u16;
typedef unsigned long long u64;
typedef __attribute__((ext_vector_type(8))) short bf16x8;
typedef __attribute__((ext_vector_type(4))) float f32x4;

__device__ __forceinline__ u16 f2bf(float f) {
  __hip_bfloat16 h = __float2bfloat16(f);
  union { __hip_bfloat16 h; u16 u; } c; c.h = h; return c.u;
}

// fast GELU: 0.5x(1+erf(x/sqrt2)), erf via Abramowitz-Stegun 7.1.26 (|err|<=1.5e-7)
__device__ __forceinline__ float gelu_f(float v) {
  float z = fabsf(v) * 0.70710678118654752f;
  float t = __builtin_amdgcn_rcpf(1.0f + 0.3275911f * z);
  float poly = t * (0.254829592f +
               t * (-0.284496736f +
               t * (1.421413741f +
               t * (-1.453152027f +
               t * 1.061405429f))));
  float ez = __expf(-z * z);
  float erfz = 1.0f - poly * ez;
  erfz = copysignf(erfz, v);
  return 0.5f * v * (1.0f + erfz);
}

__device__ __forceinline__ void async_copy16(const void* g, void* l) {
  __builtin_amdgcn_global_load_lds(
      (const __attribute__((address_space(1))) unsigned int*)g,
      (__attribute__((address_space(3))) unsigned int*)l, 16, 0, 0);
}

// opaque LDS read (rule #18 discipline): ordering enforced by our asm waits
__device__ __forceinline__ bf16x8 ds_read16(const char* p) {
  bf16x8 r;
  asm volatile("ds_read_b128 %0, %1"
               : "=&v"(r)
               : "v"((const __attribute__((address_space(3))) char*)p));
  return r;
}

#define LGKM0()                                                                   \
  do {                                                                            \
    asm volatile("s_waitcnt lgkmcnt(0)" ::: "memory");                            \
    __builtin_amdgcn_sched_barrier(0);                                            \
  } while (0)
#define VMW0() asm volatile("s_waitcnt vmcnt(0)" ::: "memory")
#define BAR() asm volatile("s_barrier" ::: "memory")

// generic 64x64 fp32->bf16 transpose tile body (shared by prep W1T and ffn1 W2T)
__device__ __forceinline__ void transpose_tile(const float* __restrict__ src,
                                               u16* __restrict__ dst, int R, int C,
                                               int bxy, int tid, float (*tile)[65]) {
  int nbx = C >> 6;
  int bx = bxy % nbx, by = bxy / nbx;
  int r0 = by * 64, c0 = bx * 64;
  int lr = tid >> 4, lc4 = (tid & 15) * 4;
#pragma unroll
  for (int p = 0; p < 4; ++p) {
    float4 v = *(const float4*)(src + (size_t)(r0 + p * 16 + lr) * C + c0 + lc4);
    tile[p * 16 + lr][lc4 + 0] = v.x;
    tile[p * 16 + lr][lc4 + 1] = v.y;
    tile[p * 16 + lr][lc4 + 2] = v.z;
    tile[p * 16 + lr][lc4 + 3] = v.w;
  }
  __syncthreads();
  int oc = tid >> 3, orr = (tid & 7) * 8;
#pragma unroll
  for (int p = 0; p < 2; ++p) {
    int c = p * 32 + oc;
    u16 h[8];
#pragma unroll
    for (int j = 0; j < 8; ++j) h[j] = f2bf(tile[orr + j][c]);
    *(uint4*)(dst + (size_t)(c0 + c) * R + r0 + orr) = *(uint4*)h;
  }
}

// ===== K1: merged router (bid<4096) + W1 transpose (bid>=4096) =====
// routers do NOT fence — kernel boundary is the sync point (R12/R16 lesson).
__global__ __launch_bounds__(256) void prep_k(const float* __restrict__ x,
                                              const float* __restrict__ Wg,
                                              const float* __restrict__ W1,
                                              float* __restrict__ probs,
                                              float* __restrict__ probsT,
                                              u16* __restrict__ xb,
                                              u16* __restrict__ w1t,
                                              u64* __restrict__ key,
                                              int* cnt, int* cnt2, int* gates) {
  __shared__ float tile[64][65];
  int bid = blockIdx.x, tid = threadIdx.x;
  if (bid < 4096) {
    if (tid < 4) key[bid * 4 + tid] = 0ull;
    if (bid == 0 && tid < NE) { cnt[tid] = 0; cnt2[tid] = 0; }
    if (bid == 0 && tid >= 8 && tid < 10) gates[tid - 8] = 0;
    int wid = tid >> 6, lane = tid & 63;
    int t = bid * 4 + wid;
    const float* xr = x + (size_t)t * DIM;
    u16* xbr = xb + (size_t)t * DIM;
    double acc[NE] = {0, 0, 0, 0, 0, 0, 0, 0};
#pragma unroll
    for (int it = 0; it < DIM / 64; ++it) {
      int d = it * 64 + lane;
      float xv = xr[d];
      xbr[d] = f2bf(xv);
      const float4* wrow = (const float4*)(Wg + (size_t)d * NE);
      float4 w0 = wrow[0], w1 = wrow[1];
      acc[0] += (double)xv * (double)w0.x;
      acc[1] += (double)xv * (double)w0.y;
      acc[2] += (double)xv * (double)w0.z;
      acc[3] += (double)xv * (double)w0.w;
      acc[4] += (double)xv * (double)w1.x;
      acc[5] += (double)xv * (double)w1.y;
      acc[6] += (double)xv * (double)w1.z;
      acc[7] += (double)xv * (double)w1.w;
    }
#pragma unroll
    for (int e = 0; e < NE; ++e)
      for (int o = 32; o > 0; o >>= 1) acc[e] += __shfl_down(acc[e], o, 64);
    if (lane == 0) {
      float l[NE], mx = -3.0e38f;
#pragma unroll
      for (int e = 0; e < NE; ++e) { l[e] = (float)acc[e]; mx = fmaxf(mx, l[e]); }
      float s = 0.f;
#pragma unroll
      for (int e = 0; e < NE; ++e) { l[e] = expf(l[e] - mx); s += l[e]; }
      float inv = 1.0f / s;
#pragma unroll
      for (int e = 0; e < NE; ++e) {
        float p = l[e] * inv;
        probs[(size_t)t * NE + e] = p;
        probsT[(size_t)e * T_TOK + t] = p;
      }
    }
  } else {
    int tz = bid - 4096;            // 0..4095
    int z = tz >> 9, bxy = tz & 511;
    transpose_tile(W1 + (size_t)z * DIM * FF, w1t + (size_t)z * DIM * FF,
                   DIM, FF, bxy, tid, tile);
  }
}

// ===== K2: merged topk(8 blocks) + assign+slot (64 blocks, internal gate) =====
__global__ __launch_bounds__(256) void moe_route_k(const float* __restrict__ probsT,
                                                   const float* __restrict__ probs,
                                                   u64* __restrict__ key,
                                                   int* __restrict__ tok2exp,
                                                   float* __restrict__ wgt,
                                                   int* cnt, int* cnt2,
                                                   int* __restrict__ list,
                                                   int* basep, int* wl1, int* wl2,
                                                   int* gates) {
  __shared__ float pcol[T_TOK];
  __shared__ unsigned whist[8][2048];
  __shared__ unsigned hist[2048];
  __shared__ unsigned bcast[2];
  __shared__ unsigned wsum[4];
  __shared__ int wps[4];
  int bid = blockIdx.x, tid = threadIdx.x, wid = tid >> 6, lane = tid & 63;
  if (bid < 8) {
    int e = bid;
    const float4* src4 = (const float4*)(probsT + (size_t)e * T_TOK);
    for (int i = tid; i < T_TOK / 4; i += 256) ((float4*)pcol)[i] = src4[i];
    for (int i = tid; i < 8 * 2048; i += 256) ((unsigned*)whist)[i] = 0;
    unsigned prefix = 0, remaining = CAPK;
#pragma unroll 1
    for (int lvl = 0; lvl < 3; ++lvl) {
      int nb = (lvl == 2) ? 1024 : 2048;
      if (lvl == 0) {
        __syncthreads();
        for (int i = tid; i < T_TOK; i += 256)
          atomicAdd(&whist[wid][__float_as_uint(pcol[i]) >> 21], 1u);
        __syncthreads();
        for (int j = tid; j < 2048; j += 256) {
          unsigned s2 = 0;
#pragma unroll
          for (int w = 0; w < 8; ++w) s2 += whist[w][j];
          hist[j] = s2;
        }
        __syncthreads();
      } else {
        for (int i = tid; i < 2048; i += 256) hist[i] = 0;
        __syncthreads();
        for (int i = tid; i < T_TOK; i += 256) {
          unsigned k = __float_as_uint(pcol[i]);
          bool m = (lvl == 1) ? ((k >> 21) == prefix) : ((k >> 10) == prefix);
          if (m) atomicAdd(&hist[(lvl == 1) ? ((k >> 10) & 2047u) : (k & 1023u)], 1u);
        }
        __syncthreads();
      }
      int nper = nb / 256;
      unsigned cv = 0;
      for (int j = 0; j < nper; ++j) cv += hist[tid * nper + j];
      unsigned s = cv;
#pragma unroll
      for (int o = 1; o < 64; o <<= 1) {
        unsigned tv = __shfl_down(s, o, 64);
        if (lane + o < 64) s += tv;
      }
      if (lane == 0) wsum[wid] = s;
      __syncthreads();
      unsigned above = 0;
      for (int w = wid + 1; w < 4; ++w) above += wsum[w];
      unsigned Sincl = s + above, Sexcl = Sincl - cv;
      if (Sincl >= remaining && Sexcl < remaining) {
        unsigned rem2 = remaining - Sexcl, cum2 = 0;
        for (int j = nper - 1; j >= 0; --j) {
          unsigned h = hist[tid * nper + j];
          if (cum2 + h >= rem2) { bcast[0] = (unsigned)(tid * nper + j); bcast[1] = rem2 - cum2; break; }
          cum2 += h;
        }
      }
      __syncthreads();
      unsigned b = bcast[0];
      remaining = bcast[1];
      prefix = (lvl == 0) ? b : (lvl == 1) ? ((prefix << 11) | b) : ((prefix << 10) | b);
      __syncthreads();
    }
    unsigned vk = prefix;
    int need = (int)remaining;
    const int CH = T_TOK / 256;
    int i0 = tid * CH;
    int myt = 0;
    for (int i = i0; i < i0 + CH; ++i)
      myt += (__float_as_uint(pcol[i]) == vk);
    int p = myt;
#pragma unroll
    for (int o = 1; o < 64; o <<= 1) {
      int tv = __shfl_up(p, o, 64);
      if (lane >= o) p += tv;
    }
    if (lane == 63) wps[wid] = p;
    __syncthreads();
    int wo = 0;
    for (int w = 0; w < wid; ++w) wo += wps[w];
    int run = wo + p - myt;
    u64 ebits = (u64)(7 - e);
    for (int i = i0; i < i0 + CH; ++i) {
      unsigned k = __float_as_uint(pcol[i]);
      bool sv = false;
      if (k > vk) sv = true;
      else if (k == vk) { if (run < need) sv = true; run++; }
      if (sv) atomicMax(&key[i], ((u64)k << 3) | ebits);
    }
    __threadfence();
    __syncthreads();
    if (tid == 0) atomicAdd(&gates[0], 1);
  } else {
    if (tid == 0) {
      while (atomicAdd(&gates[0], 0) < 8) __builtin_amdgcn_s_sleep(8);
    }
    __syncthreads();
    __threadfence();
    int gid = (bid - 8) * 256 + tid;
    u64 k = key[gid];
    int best;
    float bp;
    if (k) {
      best = 7 - (int)(k & 7);
      bp = __uint_as_float((unsigned)(k >> 3));
    } else {
      best = 0; bp = -3.0e38f;
#pragma unroll
      for (int e = 0; e < NE; ++e) {
        float p = probs[(size_t)gid * NE + e];
        if (p > bp) { bp = p; best = e; }
      }
    }
    tok2exp[gid] = best;
    wgt[gid] = bp;
#pragma unroll
    for (int e = 0; e < NE; ++e) {
      u64 m = __ballot(best == e);
      if (best == e && lane == __ffsll(m) - 1) atomicAdd(&cnt[e], (int)__popcll(m));
    }
    __threadfence();
    __syncthreads();
    if (tid == 0) atomicAdd(&gates[1], 1);
    if (tid == 0) {
      while (atomicAdd(&gates[1], 0) < 64) __builtin_amdgcn_s_sleep(8);
    }
    __syncthreads();
    __threadfence();
    int c[NE];
#pragma unroll
    for (int e = 0; e < NE; ++e) c[e] = cnt[e];
    if (gid < NE) {
      int r = 0;
      for (int e = 0; e < gid; ++e) r += c[e];
      basep[gid] = r;
    }
    if (gid < WL1SZ) {
      int e = gid & 7, j = gid >> 3;      // j 0..511
      int mte = (c[e] + 127) >> 7;
      wl1[gid] = (j < mte * 16) ? (e | ((j >> 4) << 4) | ((j & 15) << 12)) : -1;
    }
    if (gid >= WL1SZ && gid < WL1SZ + WL2SZ) {
      int g2 = gid - WL1SZ;
      int e = g2 & 7, j = g2 >> 3;        // j 0..255
      int mte = (c[e] + 127) >> 7;
      wl2[g2] = (j < mte * 8) ? (e | ((j >> 3) << 4) | ((j & 7) << 12)) : -1;
    }
    int te = tok2exp[gid];
    int bp_e = 0;
#pragma unroll
    for (int e = 0; e < NE; ++e) if (e < te) bp_e += c[e];
    int sl = 0;
#pragma unroll
    for (int e = 0; e < NE; ++e) {
      u64 m = __ballot(te == e);
      if (te == e) {
        int leader = __ffsll(m) - 1;
        int rank = __popcll(m & ((1ull << lane) - 1));
        int b = 0;
        if (lane == leader) b = atomicAdd(&cnt2[e], (int)__popcll(m));
        b = __shfl(b, leader, 64);
        sl = bp_e + b + rank;
      }
    }
    list[sl] = gid;
  }
}

// ===== FFN: R10/R17 config — 128x128 tile, BK=64, SINGLE 32KB buffer, 4 blocks/CU =====
// per tile: {stage -> vmcnt(0)+bar -> read/MFMA x2 -> bar}; cross-block wave
// rotation (m114) hides the drains. Swizzled LDS, asm ds_read, setprio,
// operand-swapped MFMA, XCD worklists.
// EPI=0: H[slot] = GELU(xb[tok] @ W1t^T); blocks >= WL1SZ do W2 transpose
// EPI=1: out[tok] = wgt * (H[slot] @ W2t^T)

#define MF(M, N_, AV, BV) acc[M][N_] = __builtin_amdgcn_mfma_f32_16x16x32_bf16(BV, AV, acc[M][N_], 0, 0, 0)

#define STG(kt)                                                                   \
  do {                                                                            \
    char* dA = sm;                                                                \
    char* dB = sm + 16384;                                                        \
    size_t ko = (size_t)(kt) * 128;                                               \
    async_copy16(aP0 + ko,      dA + tid * 16);                                   \
    async_copy16(aP1 + ko,      dA + 4096 + tid * 16);                            \
    async_copy16(aP0 + ko + 64, dA + 8192 + tid * 16);                            \
    async_copy16(aP1 + ko + 64, dA + 12288 + tid * 16);                           \
    async_copy16(bP0 + ko,      dB + tid * 16);                                   \
    async_copy16(bP1 + ko,      dB + 4096 + tid * 16);                            \
    async_copy16(bP0 + ko + 64, dB + 8192 + tid * 16);                            \
    async_copy16(bP1 + ko + 64, dB + 12288 + tid * 16);                           \
  } while (0)

#define DSRD(kkoff)                                                               \
  do {                                                                            \
    const char* pa = sm + (kkoff) + wr * 4096 + laneOff;                          \
    const char* pb = sm + 16384 + (kkoff) + wc * 4096 + laneOff;                  \
    a0 = ds_read16(pa);        a1 = ds_read16(pa + 1024);                         \
    a2 = ds_read16(pa + 2048); a3 = ds_read16(pa + 3072);                         \
    b0 = ds_read16(pb);        b1 = ds_read16(pb + 1024);                         \
    b2 = ds_read16(pb + 2048); b3 = ds_read16(pb + 3072);                         \
  } while (0)

#define MFMA16()                                                                  \
  do {                                                                            \
    __builtin_amdgcn_s_setprio(1);                                                \
    MF(0, 0, a0, b0); MF(0, 1, a0, b1); MF(0, 2, a0, b2); MF(0, 3, a0, b3);       \
    MF(1, 0, a1, b0); MF(1, 1, a1, b1); MF(1, 2, a1, b2); MF(1, 3, a1, b3);       \
    MF(2, 0, a2, b0); MF(2, 1, a2, b1); MF(2, 2, a2, b2); MF(2, 3, a2, b3);       \
    MF(3, 0, a3, b0); MF(3, 1, a3, b1); MF(3, 2, a3, b2); MF(3, 3, a3, b3);       \
    __builtin_amdgcn_s_setprio(0);                                                \
  } while (0)

template <int EPI>
__global__ __launch_bounds__(256, 4) void ffn_k(const u16* __restrict__ A,
                                                const u16* __restrict__ Bm,
                                                void* __restrict__ Out,
                                                const int* __restrict__ list,
                                                const float* __restrict__ wgt,
                                                const int* __restrict__ basep,
                                                const int* __restrict__ cnt,
                                                const int* __restrict__ wl,
                                                const float* __restrict__ W2f,
                                                u16* __restrict__ w2t) {
  constexpr int K = EPI ? FF : DIM;
  constexpr int N = EPI ? DIM : FF;
  constexpr int KT = K / 64;

  __shared__ u16 smem[16384];   // 32 KiB: GEMM buffer / transpose tile alias
  __shared__ int toks[128];
  __shared__ float wsc[128];
  char* const sm = (char*)smem;
  const int tid = threadIdx.x;

  if (EPI == 0 && blockIdx.x >= WL1SZ) {
    // ---- W2 transpose role: fp32 [E][F][D] -> bf16 [E][D][F] ----
    int tz = blockIdx.x - WL1SZ;    // 0..4095
    int z = tz >> 9, bxy = tz & 511;
    transpose_tile(W2f + (size_t)z * FF * DIM, w2t + (size_t)z * FF * DIM,
                   FF, DIM, bxy, tid, (float (*)[65])sm);
    return;
  }

  const int wle = wl[blockIdx.x];
  if (wle < 0) return;
  const int e = wle & 15, mt = (wle >> 4) & 255, nt = wle >> 12;
  const int ce = cnt[e];
  const int be = basep[e];

  if (tid < 128) {
    int r = mt * 128 + tid;
    int tk = (r < ce) ? list[be + r] : list[be];
    toks[tid] = tk;
    if (EPI == 1) wsc[tid] = wgt[tk];
  }
  __syncthreads();

  const int wid = tid >> 6, lane = tid & 63;
  const int wr = wid >> 1, wc = wid & 1;
  // swizzled frag-read offset (2 rows per 128B line, XOR on line&3) — verified R4-R17
  const int laneOff = ((lane & 15) >> 1) * 128 + (lane & 1) * 64 +
                      (((lane >> 4) << 4) ^ ((((lane & 15) >> 1) & 3) << 4));

  // staging: thread covers rows r0 and r0+64; inverse-swizzled source column
  const int r0 = 2 * (tid >> 3) + ((tid & 7) >> 2);     // 0..63
  const int cbl = ((tid & 3) << 4) ^ (((tid >> 3) & 3) << 4);
  const char *aP0, *aP1;
  if (EPI == 0) {
    aP0 = (const char*)(A + (size_t)toks[r0] * K) + cbl;
    aP1 = (const char*)(A + (size_t)toks[r0 + 64] * K) + cbl;
  } else {
    aP0 = (const char*)(A + ((size_t)be + mt * 128 + r0) * K) + cbl;
    aP1 = (const char*)(A + ((size_t)be + mt * 128 + r0 + 64) * K) + cbl;
  }
  const char* bP0 = (const char*)(Bm + ((size_t)e * N + nt * 128 + r0) * K) + cbl;
  const char* bP1 = (const char*)(Bm + ((size_t)e * N + nt * 128 + r0 + 64) * K) + cbl;

  f32x4 acc[4][4];
#pragma unroll
  for (int m = 0; m < 4; ++m)
#pragma unroll
    for (int n = 0; n < 4; ++n) acc[m][n] = (f32x4){0.f, 0.f, 0.f, 0.f};

  bf16x8 a0, a1, a2, a3, b0, b1, b2, b3;

#pragma unroll 1
  for (int kt = 0; kt < KT; ++kt) {
    STG(kt);          // stage tile kt into the single buffer
    VMW0();
    BAR();            // tile visible to all waves
    DSRD(0);          // kk0 frags
    LGKM0();
    MFMA16();
    DSRD(8192);       // kk1 frags
    LGKM0();
    MFMA16();
    BAR();            // all reads done before next stage overwrites
  }

  // epilogue: operand-swap => acc reg index runs along output cols -> vector stores
  const int lc = lane & 15, lq = (lane >> 4) * 4;
#pragma unroll
  for (int m = 0; m < 4; ++m) {
    int trow = wr * 64 + m * 16 + lc;
    int grow = mt * 128 + trow;
    if (grow < ce) {
      if (EPI == 0) {
        size_t rowoff = (size_t)(be + grow) * FF + nt * 128 + wc * 64 + lq;
#pragma unroll
        for (int n = 0; n < 4; ++n) {
          ushort4 h4;
          h4.x = f2bf(gelu_f(acc[m][n][0]));
          h4.y = f2bf(gelu_f(acc[m][n][1]));
          h4.z = f2bf(gelu_f(acc[m][n][2]));
          h4.w = f2bf(gelu_f(acc[m][n][3]));
          *(ushort4*)((u16*)Out + rowoff + n * 16) = h4;
        }
      } else {
        float w = wsc[trow];
        size_t rowoff = (size_t)toks[trow] * DIM + nt * 128 + wc * 64 + lq;
#pragma unroll
        for (int n = 0; n < 4; ++n) {
          float4 o = make_float4(w * acc[m][n][0], w * acc[m][n][1],
                                 w * acc[m][n][2], w * acc[m][n][3]);
          *(float4*)((float*)Out + rowoff + n * 16) = o;
        }
      }
    }
  }
}

extern "C" void kernel_launch(void* const* d_in, const int* in_sizes, int n_in,
                              void* d_out, int out_size, void* d_ws, size_t ws_size,
                              hipStream_t stream) {
  (void)in_sizes; (void)n_in; (void)out_size; (void)ws_size;
  const float* x  = (const float*)d_in[0];
  const float* Wg = (const float*)d_in[1];
  const float* W1 = (const float*)d_in[2];
  const float* W2 = (const float*)d_in[3];
  float* out = (float*)d_out;

  char* ws = (char*)d_ws;
  size_t off = 0;
  auto alloc = [&](size_t bytes) -> void* {
    void* p = ws + off;
    off += (bytes + 255) & ~(size_t)255;
    return p;
  };
  u16* xb   = (u16*)alloc((size_t)T_TOK * DIM * 2);         // 32 MB
  u16* w1t  = (u16*)alloc((size_t)NE * FF * DIM * 2);       // 32 MB  [E][F][D]
  u16* w2t  = (u16*)alloc((size_t)NE * DIM * FF * 2);       // 32 MB  [E][D][F]
  u16* H    = (u16*)alloc((size_t)(T_TOK + 256) * FF * 2);  // 65 MB, padded
  float* probs  = (float*)alloc((size_t)T_TOK * NE * 4);
  float* probsT = (float*)alloc((size_t)NE * T_TOK * 4);
  u64* key      = (u64*)alloc((size_t)T_TOK * 8);
  float* wgt    = (float*)alloc((size_t)T_TOK * 4);
  int* tok2exp  = (int*)alloc((size_t)T_TOK * 4);
  int* list     = (int*)alloc((size_t)T_TOK * 4);
  int* cnt      = (int*)alloc(64);
  int* cnt2     = (int*)alloc(64);
  int* basep    = (int*)alloc(64);
  int* gates    = (int*)alloc(64);
  int* wl1      = (int*)alloc(WL1SZ * 4);
  int* wl2      = (int*)alloc(WL2SZ * 4);

  prep_k<<<4096 + 4096, 256, 0, stream>>>(x, Wg, W1, probs, probsT, xb, w1t,
                                          key, cnt, cnt2, gates);
  moe_route_k<<<72, 256, 0, stream>>>(probsT, probs, key, tok2exp, wgt, cnt, cnt2,
                                      list, basep, wl1, wl2, gates);
  ffn_k<0><<<WL1SZ + NB_W2T, 256, 0, stream>>>(xb, w1t, H, list, wgt, basep, cnt, wl1,
                                               W2, w2t);
  ffn_k<1><<<WL2SZ, 256, 0, stream>>>(H, w2t, out, list, wgt, basep, cnt, wl2,
                                      W2, w2t);
}